// Round 9
// baseline (167.753 us; speedup 1.0000x reference)
//
#include <hip/hip_runtime.h>

// ---------------------------------------------------------------------------
// SelfAttentionLayer: out[b,s,c*16+h] = softmax_k( (q.k)/32 masked ) @ v
// R15 = R12 + X double-buffer with W pipelined through REGISTERS (T14).
// R13/R14 post-mortem: both failed on a mis-sized W buffer (96x64 = 6144 u16,
// not 3072) -> WsA/WsB overlapped + overflowed smem. Correctly sized, dual
// double-buffering = 91 KB -> 1 block/CU (R11 disaster). Fix: keep Ws SINGLE
// (12 KB); prefetch W(t+1) into regs (wA/wB) at iter-t top; commit via
// ds_write at iter-(t+1) top after a CHEAP vmcnt(0) (ops issued a full
// compute span ago). X(t+1) DMA issued same place, drained by same vmcnt(0).
// No counted-N waits, no extra barriers; the existing lgkm(0)+barrier1
// publishes both. LDS 77 KB -> 2 blocks/CU preserved. Attn phase R12-verbatim.
// ---------------------------------------------------------------------------

typedef unsigned short u16;
typedef unsigned int u32;
typedef __attribute__((ext_vector_type(8))) short short8;
typedef __attribute__((ext_vector_type(4))) short short4v;
typedef __attribute__((ext_vector_type(4))) float floatx4;

#if __has_builtin(__builtin_amdgcn_mfma_f32_16x16x16bf16_1k)
#define MFMA16(A, B, C) __builtin_amdgcn_mfma_f32_16x16x16bf16_1k(A, B, C, 0, 0, 0)
#elif __has_builtin(__builtin_amdgcn_mfma_f32_16x16x16_bf16)
#define MFMA16(A, B, C) __builtin_amdgcn_mfma_f32_16x16x16_bf16(A, B, C, 0, 0, 0)
#else
__device__ __forceinline__ floatx4 mfma16_asm(short4v a, short4v b, floatx4 c) {
  floatx4 d;
  asm volatile("v_mfma_f32_16x16x16_bf16 %0, %1, %2, %3"
               : "=v"(d) : "v"(a), "v"(b), "v"(c));
  return d;
}
#define MFMA16(A, B, C) mfma16_asm(A, B, C)
#endif

#if __has_builtin(__builtin_amdgcn_exp2f)
#define EXP2(x) __builtin_amdgcn_exp2f(x)
#else
#define EXP2(x) __expf((x) * 0.6931471805599453f)
#endif

#define QSCALE 0.045084220f  // log2(e)/32, folded into Q

__device__ __forceinline__ u16 f2bf(float f) {
  union { float f; u32 u; } x; x.f = f;
  u32 r = x.u + 0x7fffu + ((x.u >> 16) & 1u);  // RNE
  return (u16)(r >> 16);
}
__device__ __forceinline__ float bf2f(u16 u) {
  union { u32 u; float f; } x; x.u = ((u32)u) << 16;
  return x.f;
}

// async global->LDS, 16B per lane; LDS dest = wave-uniform base + lane*16
__device__ __forceinline__ void gload16(const void* g, void* l) {
  typedef __attribute__((address_space(1))) const unsigned int gq;
  typedef __attribute__((address_space(3))) unsigned int lq;
  __builtin_amdgcn_global_load_lds((gq*)(size_t)g, (lq*)(size_t)l, 16, 0, 0);
}

#define GK 1024
#define QKS 20   // Qs/Ks row stride (u16): 8B-aligned frags, conflict-free
#define VTS 264  // Vt row stride (u16): 2-way-max banks (free)

// ---------------------------------------------------------------------------
// Merged cast f32 -> bf16: X (8192 blocks), Wq/Wk/Wv (1024 blocks each)
// ---------------------------------------------------------------------------
__global__ __launch_bounds__(256) void cast_all(const float* __restrict__ x,
                                                const float* __restrict__ wq,
                                                const float* __restrict__ wk,
                                                const float* __restrict__ wv,
                                                u16* __restrict__ XB,
                                                u16* __restrict__ WB) {
  int bid = blockIdx.x;
  const float* src; u16* dst; int off;
  if (bid < 8192)       { src = x;  dst = XB;                 off = bid; }
  else if (bid < 9216)  { src = wq; dst = WB;                 off = bid - 8192; }
  else if (bid < 10240) { src = wk; dst = WB + 1024 * 1024;   off = bid - 9216; }
  else                  { src = wv; dst = WB + 2 * 1024 * 1024; off = bid - 10240; }
  int i = (off * 256 + threadIdx.x) * 4;
  float4 v = *(const float4*)(src + i);
  u32 lo = (u32)f2bf(v.x) | ((u32)f2bf(v.y) << 16);
  u32 hi = (u32)f2bf(v.z) | ((u32)f2bf(v.w) << 16);
  uint2 o; o.x = lo; o.y = hi;
  *(uint2*)(dst + i) = o;
}

// ---------------------------------------------------------------------------
// Attn kt-loop (R5-verified math, LDS sources): S^T = MFMA(K, Qscaled);
// p = exp2(st) trunc-packed via v_perm; l via MFMA(ones,p); O^T += MFMA(V^T,p)
// qt=2: each of the 8 waves owns a 32-row q-strip. T5 setprio per cluster.
// ---------------------------------------------------------------------------
template <bool MASKED>
__device__ __forceinline__ void attn_loop2(const u16* __restrict__ Ks,
                                           const u16* __restrict__ Vt,
                                           const short4v* bq, const float* mqv,
                                           const float* m_s,
                                           floatx4* oacc, floatx4* lacc,
                                           int col, int quad) {
  const short4v ones = {(short)0x3F80, (short)0x3F80, (short)0x3F80, (short)0x3F80};
#pragma unroll 4
  for (int kt = 0; kt < 16; kt++) {
    const int kb = kt * 16;
    short4v ak = *(const short4v*)(Ks + (kb + col) * QKS + quad * 4);
    short4v av = *(const short4v*)(Vt + col * VTS + kb + quad * 4);
    float mk[4];
    if (MASKED) {
#pragma unroll
      for (int i = 0; i < 4; i++) mk[i] = m_s[kb + quad * 4 + i];
    }
#pragma unroll
    for (int qt = 0; qt < 2; qt++) {
      __builtin_amdgcn_s_setprio(1);
      floatx4 z = {0.f, 0.f, 0.f, 0.f};
      floatx4 st = MFMA16(ak, bq[qt], z);
      float e[4];
#pragma unroll
      for (int i = 0; i < 4; i++) {
        e[i] = EXP2(st[i]);
        if (MASKED) e[i] = (mqv[qt] * mk[i] > 0.f) ? e[i] : 0.f;
      }
      union { u32 u[2]; short4v s; } pk;
      pk.u[0] = __builtin_amdgcn_perm(__float_as_uint(e[1]), __float_as_uint(e[0]), 0x07060302u);
      pk.u[1] = __builtin_amdgcn_perm(__float_as_uint(e[3]), __float_as_uint(e[2]), 0x07060302u);
      lacc[qt] = MFMA16(ones, pk.s, lacc[qt]);
      oacc[qt] = MFMA16(av, pk.s, oacc[qt]);
      __builtin_amdgcn_s_setprio(0);
    }
  }
}

// ---------------------------------------------------------------------------
// Fused kernel. Block = (c0 = (bid>>5)*2 heads, b = bid&31); grid 1024.
// Same-b blocks -> same XCD (bid%8 = b%8): XB[b] (512 KB) stays L2-resident.
// Phase 1 (GEMM): [256,96] = X[b][256,1024] @ Wslice[96,1024]^T.
//   Tile t: X in Xs[t&1] (double-buffered), W in single Ws. Per iter t:
//     vmcnt(0)  [cheap: drains X(t) DMA + W(t) regs, issued a full compute
//                span ago]
//     ds_write Ws <- wA/wB  [W(t) into LDS; Ws freed by barrier2(t-1)]
//     issue X(t+1) DMA -> Xs[!(t&1)]; load W(t+1) -> wA/wB   [stay in flight]
//     lgkm(0); barrier1  [tile t fully published]
//     16 ds_read_b128 + 24 MFMA
//     lgkm(0); barrier2  [buffers released]
//   XOR swizzle (proven): phys chunk p of row holds logical p^(row&7).
// Phase 2 (x2 heads, sequential): R12-verbatim (incl. T5 setprio).
// LDS: Xs0@0 (32KB), Xs1@32768B, Ws@65536B (12288B) = 77824 B + m_s 1024 B
// = 78848 B -> 2 blocks/CU (157.7 of 160 KB). VGPR ~72 (cap 128).
// ---------------------------------------------------------------------------
__global__ __launch_bounds__(512, 4) void fused_qkv_attn(const u16* __restrict__ XB,
                                                         const u16* __restrict__ WB,
                                                         const float* __restrict__ mask,
                                                         float* __restrict__ out) {
  __shared__ __align__(16) u16 smem[38912];  // 77824 B
  // GEMM: Xs0@0 (256*64=16384 u16), Xs1@16384, Ws@32768 (96*64=6144 u16)
  // attn (inside Xs0): Qs@0 (256*20), Ks@5120, Vt@10240 (16*264, ends 14464),
  //       l_s@14464 (256 f32, ends u16 14976 < 16384), ot overlays @0 (16*257 f32)
  __shared__ float m_s[256];

  const int bid = blockIdx.x;
  const int b = bid & 31;
  const int c0 = (bid >> 5) * 2;       // first of 2 heads
  const int t = threadIdx.x;
  const int wave = t >> 6;             // 0..7
  const int lane = t & 63;
  const int col = lane & 15;
  const int quad = lane >> 4;

  u16* const Xs0 = smem;
  u16* const Xs1 = smem + 16384;
  u16* const Ws  = smem + 32768;

  float mv = (t < 256) ? mask[b * 256 + t] : 1.0f;
  if (t < 256) m_s[t] = mv;
  const int allones = __syncthreads_and(mv > 0.f);

  // ---------------- phase 1: GEMM ----------------
  const int r_loc = lane >> 3;          // row within 8-row gload group
  const int sch = (lane & 7) ^ r_loc;   // XOR-swizzled source k-chunk

  // X: wave w stages its own 32 rows (4 gload16 of 8 rows each)
  const size_t xsrc = ((size_t)b * 256 + wave * 32 + r_loc) * GK + sch * 8;
  const int xdst = wave * 2048;         // u16: (wave*32 rows)*64; + g*512

  // W: 12 groups of 8 rows; group g -> nt = g>>1 (nt = head*3 + mat),
  // WB row = (nt%3)*1024 + (c0 + nt/3)*16 + (g&1)*8 + r_loc.
  // wave w owns group w; waves 0-3 also own group 8+w. 16 B per lane.
  const int gA = wave;
  const int ntA = gA >> 1;
  const size_t wsrcA =
      ((size_t)((ntA % 3) * 1024 + (c0 + ntA / 3) * 16 + (gA & 1) * 8 + r_loc)) * GK + sch * 8;
  size_t wsrcB = 0;
  const int gB = 8 + wave;
  if (wave < 4) {
    const int ntB = gB >> 1;
    wsrcB = ((size_t)((ntB % 3) * 1024 + (c0 + ntB / 3) * 16 + (gB & 1) * 8 + r_loc)) * GK + sch * 8;
  }
  // per-lane Ws commit addresses (linear, same layout gload16 would produce)
  u16* const wdA = Ws + gA * 512 + lane * 8;
  u16* const wdB = Ws + gB * 512 + lane * 8;

  floatx4 acc[2][6] = {};  // [mt][nt]: m = wave*32+mt*16; nt = head*3+{Q,K,V}

  // prologue: issue tile 0 X-DMA -> Xs0; load W(0) into regs
#pragma unroll
  for (int g = 0; g < 4; g++)
    gload16(XB + xsrc + (size_t)g * 8 * GK, Xs0 + xdst + g * 512);
  __builtin_amdgcn_sched_barrier(0);
  uint4 wA = *(const uint4*)(WB + wsrcA);
  uint4 wB = {};
  if (wave < 4) wB = *(const uint4*)(WB + wsrcB);

  auto gemm_step = [&](int k0n, const u16* Xc, u16* Xn) {
    // drain X(t) DMA + W(t) regs (issued a full compute span ago -> cheap)
    asm volatile("s_waitcnt vmcnt(0)" ::: "memory");
    __builtin_amdgcn_sched_barrier(0);
    // commit W(t) to LDS (Ws freed by barrier2 of t-1)
    *(uint4*)wdA = wA;
    if (wave < 4) *(uint4*)wdB = wB;
    __builtin_amdgcn_sched_barrier(0);
    // prefetch tile t+1: X via DMA into the other buffer, W into regs
    if (k0n >= 0) {
#pragma unroll
      for (int g = 0; g < 4; g++)
        gload16(XB + xsrc + (size_t)g * 8 * GK + k0n, Xn + xdst + g * 512);
      wA = *(const uint4*)(WB + wsrcA + k0n);
      if (wave < 4) wB = *(const uint4*)(WB + wsrcB + k0n);
    }
    __builtin_amdgcn_sched_barrier(0);
    asm volatile("s_waitcnt lgkmcnt(0)" ::: "memory");  // my Ws writes visible
    __builtin_amdgcn_sched_barrier(0);
    __builtin_amdgcn_s_barrier();      // barrier1: tile t fully published
    __builtin_amdgcn_sched_barrier(0);

#pragma unroll
    for (int kk = 0; kk < 2; kk++) {
      const int pos = ((kk * 4 + quad) ^ (col & 7)) * 8;
      short8 af[2], bf[6];
#pragma unroll
      for (int mt = 0; mt < 2; mt++)
        af[mt] = *(const short8*)(Xc + (wave * 32 + mt * 16 + col) * 64 + pos);
#pragma unroll
      for (int nt = 0; nt < 6; nt++)
        bf[nt] = *(const short8*)(Ws + (nt * 16 + col) * 64 + pos);
#pragma unroll
      for (int mt = 0; mt < 2; mt++)
#pragma unroll
        for (int nt = 0; nt < 6; nt++)
          acc[mt][nt] = __builtin_amdgcn_mfma_f32_16x16x32_bf16(af[mt], bf[nt], acc[mt][nt], 0, 0, 0);
    }

    asm volatile("s_waitcnt lgkmcnt(0)" ::: "memory");  // my reads of tile t done
    __builtin_amdgcn_sched_barrier(0);
    __builtin_amdgcn_s_barrier();      // barrier2: Xn (for t+2) and Ws released
    __builtin_amdgcn_sched_barrier(0);
  };

  // 16 tiles of BK=64; tile t's X in Xs[t&1]; iter computes t, prefetches t+1
#pragma unroll 1
  for (int tp = 0; tp < 8; tp++) {
    gemm_step((2 * tp + 1) * 64, Xs0, Xs1);                   // t = 2tp
    gemm_step((tp == 7) ? -1 : (2 * tp + 2) * 64, Xs1, Xs0);  // t = 2tp+1
  }

  // ---------------- phase 2: attention, 2 heads sequentially ----------------
  u16* const Qs = smem;               // [256][QKS]
  u16* const Ks = smem + 5120;        // [256][QKS]
  u16* const Vt = smem + 10240;       // [16][VTS]
  float* const l_s = (float*)(smem + 14464);
  float* const ot = (float*)smem;     // [16][257] f32, overlays Qs+Ks

#pragma unroll      // full unroll: h must be compile-time (static acc indices)
  for (int h = 0; h < 2; h++) {
    __syncthreads();  // h=0: GEMM reads done; h=1: prev ot/Vt reads done

    // C/D layout: row = m-base + quad*4 + r, col(head feature) = lane&15
#pragma unroll
    for (int mt = 0; mt < 2; mt++) {
      const int row = wave * 32 + mt * 16 + quad * 4;
#pragma unroll
      for (int r = 0; r < 4; r++) {
        Qs[(row + r) * QKS + col] = f2bf(acc[mt][3 * h + 0][r] * QSCALE);
        Ks[(row + r) * QKS + col] = f2bf(acc[mt][3 * h + 1][r]);
        Vt[col * VTS + row + r] = f2bf(acc[mt][3 * h + 2][r]);
      }
    }
    __syncthreads();

    const int q0 = wave * 32;
    short4v bq[2];
    float mqv[2];
#pragma unroll
    for (int qt = 0; qt < 2; qt++) {
      bq[qt] = *(const short4v*)(Qs + (q0 + qt * 16 + col) * QKS + quad * 4);
      mqv[qt] = m_s[q0 + qt * 16 + col];
    }

    floatx4 oacc[2] = {};
    floatx4 lacc[2] = {};
    if (allones)
      attn_loop2<false>(Ks, Vt, bq, mqv, m_s, oacc, lacc, col, quad);
    else
      attn_loop2<true>(Ks, Vt, bq, mqv, m_s, oacc, lacc, col, quad);

    __syncthreads();  // all waves out of attn before ot overlays Qs/Ks
#pragma unroll
    for (int qt = 0; qt < 2; qt++) {
      if (quad == 0) l_s[q0 + qt * 16 + col] = lacc[qt][0];
#pragma unroll
      for (int r = 0; r < 4; r++)
        ot[(quad * 4 + r) * 257 + q0 + qt * 16 + col] = oacc[qt][r];
    }
    __syncthreads();

    // epilogue: thread t -> q-row t>>1, features hb..hb+8; 32B coalesced
    const int row = t >> 1;
    const int hb = (t & 1) * 8;
    float l = l_s[row];
    float* op = out + ((size_t)b * 256 + row) * 1024 + (c0 + h) * 16 + hb;
    float o[8];
    if (allones || l > 0.f) {
      float inv = 1.0f / l;
#pragma unroll
      for (int j = 0; j < 8; j++) o[j] = ot[(hb + j) * 257 + row] * inv;
    } else {
      // fully-masked row: reference softmax of uniform -1e9 -> mean of V
#pragma unroll
      for (int j = 0; j < 8; j++) o[j] = 0.f;
      for (int k = 0; k < 256; k++)
#pragma unroll
        for (int j = 0; j < 8; j++) o[j] += bf2f(Vt[(hb + j) * VTS + k]);
#pragma unroll
      for (int j = 0; j < 8; j++) o[j] *= (1.0f / 256.0f);
    }
#pragma unroll
    for (int g = 0; g < 2; g++) {
      float4 r;
      r.x = o[g * 4 + 0]; r.y = o[g * 4 + 1]; r.z = o[g * 4 + 2]; r.w = o[g * 4 + 3];
      *(float4*)(op + g * 4) = r;
    }
  }
}

// ---------------------------------------------------------------------------
// Launch
// ---------------------------------------------------------------------------
extern "C" void kernel_launch(void* const* d_in, const int* in_sizes, int n_in,
                              void* d_out, int out_size, void* d_ws, size_t ws_size,
                              hipStream_t stream) {
  const float* x    = (const float*)d_in[0];  // [32,256,1024]
  const float* mask = (const float*)d_in[1];  // [32,256]
  const float* Wq   = (const float*)d_in[2];  // [1024,1024]
  const float* Wk   = (const float*)d_in[3];
  const float* Wv   = (const float*)d_in[4];
  float* out = (float*)d_out;

  u16* XB = (u16*)d_ws;                       // [8192][1024] bf16
  u16* WB = XB + (size_t)8192 * 1024;         // [3072][1024] (Wq,Wk,Wv stacked)

  cast_all<<<11264, 256, 0, stream>>>(x, Wq, Wk, Wv, XB, WB);
  fused_qkv_attn<<<1024, 512, 0, stream>>>(XB, WB, mask, out);
}

// Round 10
// 165.783 us; speedup vs baseline: 1.0119x; 1.0119x over previous
//
#include <hip/hip_runtime.h>

// ---------------------------------------------------------------------------
// SelfAttentionLayer: out[b,s,c*16+h] = softmax_k( (q.k)/32 masked ) @ v
// R16 = R15's dataflow (X double-buffer + W pipelined through registers,
// zero exposed staging) expressed in R12's sync style (plain __syncthreads,
// NO inline-asm waitcnt, NO sched_barrier in the hot loop).
// Evidence: R9=83.7 and R15=83.8 share only the fence style; R12=74.9 shares
// the dataflow-exposure but not the fences -> the ~9us is the fence penalty
// (m141: order-pinning defeats compiler scheduling). This round isolates the
// dataflow with compiler-friendly sync:
//   sync1 (drains X(t) DMA + W(t) regs, issued a full compute span ago)
//   -> ds_write W(t) to Ws -> sync2 (publishes Ws; free vmcnt)
//   -> issue X(t+1) DMA + W(t+1) reg loads -> compute tile t.
// Attn phase (R5 math + T5 setprio), swizzles, cast_all: R12-verbatim.
// LDS: Xs 2x32KB + Ws 12KB = 76KB + m_s 1KB -> 2 blocks/CU preserved.
// ---------------------------------------------------------------------------

typedef unsigned short u16;
typedef unsigned int u32;
typedef __attribute__((ext_vector_type(8))) short short8;
typedef __attribute__((ext_vector_type(4))) short short4v;
typedef __attribute__((ext_vector_type(4))) float floatx4;

#if __has_builtin(__builtin_amdgcn_mfma_f32_16x16x16bf16_1k)
#define MFMA16(A, B, C) __builtin_amdgcn_mfma_f32_16x16x16bf16_1k(A, B, C, 0, 0, 0)
#elif __has_builtin(__builtin_amdgcn_mfma_f32_16x16x16_bf16)
#define MFMA16(A, B, C) __builtin_amdgcn_mfma_f32_16x16x16_bf16(A, B, C, 0, 0, 0)
#else
__device__ __forceinline__ floatx4 mfma16_asm(short4v a, short4v b, floatx4 c) {
  floatx4 d;
  asm volatile("v_mfma_f32_16x16x16_bf16 %0, %1, %2, %3"
               : "=v"(d) : "v"(a), "v"(b), "v"(c));
  return d;
}
#define MFMA16(A, B, C) mfma16_asm(A, B, C)
#endif

#if __has_builtin(__builtin_amdgcn_exp2f)
#define EXP2(x) __builtin_amdgcn_exp2f(x)
#else
#define EXP2(x) __expf((x) * 0.6931471805599453f)
#endif

#define QSCALE 0.045084220f  // log2(e)/32, folded into Q

__device__ __forceinline__ u16 f2bf(float f) {
  union { float f; u32 u; } x; x.f = f;
  u32 r = x.u + 0x7fffu + ((x.u >> 16) & 1u);  // RNE
  return (u16)(r >> 16);
}
__device__ __forceinline__ float bf2f(u16 u) {
  union { u32 u; float f; } x; x.u = ((u32)u) << 16;
  return x.f;
}

// async global->LDS, 16B per lane; LDS dest = wave-uniform base + lane*16
__device__ __forceinline__ void gload16(const void* g, void* l) {
  typedef __attribute__((address_space(1))) const unsigned int gq;
  typedef __attribute__((address_space(3))) unsigned int lq;
  __builtin_amdgcn_global_load_lds((gq*)(size_t)g, (lq*)(size_t)l, 16, 0, 0);
}

#define GK 1024
#define QKS 20   // Qs/Ks row stride (u16): 8B-aligned frags, conflict-free
#define VTS 264  // Vt row stride (u16): 2-way-max banks (free)

// ---------------------------------------------------------------------------
// Merged cast f32 -> bf16: X (8192 blocks), Wq/Wk/Wv (1024 blocks each)
// ---------------------------------------------------------------------------
__global__ __launch_bounds__(256) void cast_all(const float* __restrict__ x,
                                                const float* __restrict__ wq,
                                                const float* __restrict__ wk,
                                                const float* __restrict__ wv,
                                                u16* __restrict__ XB,
                                                u16* __restrict__ WB) {
  int bid = blockIdx.x;
  const float* src; u16* dst; int off;
  if (bid < 8192)       { src = x;  dst = XB;                 off = bid; }
  else if (bid < 9216)  { src = wq; dst = WB;                 off = bid - 8192; }
  else if (bid < 10240) { src = wk; dst = WB + 1024 * 1024;   off = bid - 9216; }
  else                  { src = wv; dst = WB + 2 * 1024 * 1024; off = bid - 10240; }
  int i = (off * 256 + threadIdx.x) * 4;
  float4 v = *(const float4*)(src + i);
  u32 lo = (u32)f2bf(v.x) | ((u32)f2bf(v.y) << 16);
  u32 hi = (u32)f2bf(v.z) | ((u32)f2bf(v.w) << 16);
  uint2 o; o.x = lo; o.y = hi;
  *(uint2*)(dst + i) = o;
}

// ---------------------------------------------------------------------------
// Attn kt-loop (R5-verified math, LDS sources): S^T = MFMA(K, Qscaled);
// p = exp2(st) trunc-packed via v_perm; l via MFMA(ones,p); O^T += MFMA(V^T,p)
// qt=2: each of the 8 waves owns a 32-row q-strip. T5 setprio per cluster.
// ---------------------------------------------------------------------------
template <bool MASKED>
__device__ __forceinline__ void attn_loop2(const u16* __restrict__ Ks,
                                           const u16* __restrict__ Vt,
                                           const short4v* bq, const float* mqv,
                                           const float* m_s,
                                           floatx4* oacc, floatx4* lacc,
                                           int col, int quad) {
  const short4v ones = {(short)0x3F80, (short)0x3F80, (short)0x3F80, (short)0x3F80};
#pragma unroll 4
  for (int kt = 0; kt < 16; kt++) {
    const int kb = kt * 16;
    short4v ak = *(const short4v*)(Ks + (kb + col) * QKS + quad * 4);
    short4v av = *(const short4v*)(Vt + col * VTS + kb + quad * 4);
    float mk[4];
    if (MASKED) {
#pragma unroll
      for (int i = 0; i < 4; i++) mk[i] = m_s[kb + quad * 4 + i];
    }
#pragma unroll
    for (int qt = 0; qt < 2; qt++) {
      __builtin_amdgcn_s_setprio(1);
      floatx4 z = {0.f, 0.f, 0.f, 0.f};
      floatx4 st = MFMA16(ak, bq[qt], z);
      float e[4];
#pragma unroll
      for (int i = 0; i < 4; i++) {
        e[i] = EXP2(st[i]);
        if (MASKED) e[i] = (mqv[qt] * mk[i] > 0.f) ? e[i] : 0.f;
      }
      union { u32 u[2]; short4v s; } pk;
      pk.u[0] = __builtin_amdgcn_perm(__float_as_uint(e[1]), __float_as_uint(e[0]), 0x07060302u);
      pk.u[1] = __builtin_amdgcn_perm(__float_as_uint(e[3]), __float_as_uint(e[2]), 0x07060302u);
      lacc[qt] = MFMA16(ones, pk.s, lacc[qt]);
      oacc[qt] = MFMA16(av, pk.s, oacc[qt]);
      __builtin_amdgcn_s_setprio(0);
    }
  }
}

// ---------------------------------------------------------------------------
// Fused kernel. Block = (c0 = (bid>>5)*2 heads, b = bid&31); grid 1024.
// Same-b blocks -> same XCD (bid%8 = b%8): XB[b] (512 KB) stays L2-resident.
// Phase 1 (GEMM): [256,96] = X[b][256,1024] @ Wslice[96,1024]^T.
//   X double-buffered (Xs0/Xs1), W reg-pipelined into single Ws. Per iter t:
//     __syncthreads (sync1: drains X(t) DMA + W(t) reg loads - cheap, issued
//                    a full compute span ago)
//     ds_write Ws <- wA/wB  (commit W(t); Ws reads of t-1 done before sync1)
//     __syncthreads (sync2: Ws published; no VM issued since sync1 -> free)
//     issue X(t+1) DMA -> Xs[other] + load W(t+1) -> regs  (fly under compute)
//     compute tile t (compiler schedules ds_read/MFMA freely - no fences)
//   XOR swizzle (proven): phys chunk p of row holds logical p^(row&7).
// Phase 2 (x2 heads, sequential): R12-verbatim (incl. T5 setprio).
// LDS: Xs0@0 (32KB), Xs1@32768B, Ws@65536B (12288B) = 77824 B + m_s 1024 B
// -> 2 blocks/CU (157.7 of 160 KB). VGPR ~72 (cap 128).
// ---------------------------------------------------------------------------
__global__ __launch_bounds__(512, 4) void fused_qkv_attn(const u16* __restrict__ XB,
                                                         const u16* __restrict__ WB,
                                                         const float* __restrict__ mask,
                                                         float* __restrict__ out) {
  __shared__ __align__(16) u16 smem[38912];  // 77824 B
  // GEMM: Xs0@0 (256*64=16384 u16), Xs1@16384, Ws@32768 (96*64=6144 u16)
  // attn (inside Xs0): Qs@0 (256*20), Ks@5120, Vt@10240 (16*264, ends 14464),
  //       l_s@14464 (256 f32, ends u16 14976 < 16384), ot overlays @0 (16*257 f32)
  __shared__ float m_s[256];

  const int bid = blockIdx.x;
  const int b = bid & 31;
  const int c0 = (bid >> 5) * 2;       // first of 2 heads
  const int t = threadIdx.x;
  const int wave = t >> 6;             // 0..7
  const int lane = t & 63;
  const int col = lane & 15;
  const int quad = lane >> 4;

  u16* const Xs0 = smem;
  u16* const Xs1 = smem + 16384;
  u16* const Ws  = smem + 32768;

  float mv = (t < 256) ? mask[b * 256 + t] : 1.0f;
  if (t < 256) m_s[t] = mv;
  const int allones = __syncthreads_and(mv > 0.f);

  // ---------------- phase 1: GEMM ----------------
  const int r_loc = lane >> 3;          // row within 8-row gload group
  const int sch = (lane & 7) ^ r_loc;   // XOR-swizzled source k-chunk

  // X: wave w stages its own 32 rows (4 gload16 of 8 rows each)
  const size_t xsrc = ((size_t)b * 256 + wave * 32 + r_loc) * GK + sch * 8;
  const int xdst = wave * 2048;         // u16: (wave*32 rows)*64; + g*512

  // W: 12 groups of 8 rows; group g -> nt = g>>1 (nt = head*3 + mat),
  // WB row = (nt%3)*1024 + (c0 + nt/3)*16 + (g&1)*8 + r_loc.
  // wave w owns group w; waves 0-3 also own group 8+w. 16 B per lane.
  const int gA = wave;
  const int ntA = gA >> 1;
  const size_t wsrcA =
      ((size_t)((ntA % 3) * 1024 + (c0 + ntA / 3) * 16 + (gA & 1) * 8 + r_loc)) * GK + sch * 8;
  size_t wsrcB = 0;
  const int gB = 8 + wave;
  if (wave < 4) {
    const int ntB = gB >> 1;
    wsrcB = ((size_t)((ntB % 3) * 1024 + (c0 + ntB / 3) * 16 + (gB & 1) * 8 + r_loc)) * GK + sch * 8;
  }
  // per-lane Ws commit addresses (linear, same layout gload16 would produce)
  u16* const wdA = Ws + gA * 512 + lane * 8;
  u16* const wdB = Ws + gB * 512 + lane * 8;

  floatx4 acc[2][6] = {};  // [mt][nt]: m = wave*32+mt*16; nt = head*3+{Q,K,V}

  // prologue: issue tile 0 X-DMA -> Xs0; load W(0) into regs
#pragma unroll
  for (int g = 0; g < 4; g++)
    gload16(XB + xsrc + (size_t)g * 8 * GK, Xs0 + xdst + g * 512);
  uint4 wA = *(const uint4*)(WB + wsrcA);
  uint4 wB = {};
  if (wave < 4) wB = *(const uint4*)(WB + wsrcB);

  auto gemm_step = [&](int k0n, const u16* Xc, u16* Xn) {
    __syncthreads();                 // sync1: X(t) DMA + W(t) regs drained
    *(uint4*)wdA = wA;               // commit W(t) (Ws reads of t-1 pre-sync1)
    if (wave < 4) *(uint4*)wdB = wB;
    __syncthreads();                 // sync2: Ws published (no VM pending)
    if (k0n >= 0) {                  // prefetch t+1: flies under compute(t)
#pragma unroll
      for (int g = 0; g < 4; g++)
        gload16(XB + xsrc + (size_t)g * 8 * GK + k0n, Xn + xdst + g * 512);
      wA = *(const uint4*)(WB + wsrcA + k0n);
      if (wave < 4) wB = *(const uint4*)(WB + wsrcB + k0n);
    }

#pragma unroll
    for (int kk = 0; kk < 2; kk++) {
      const int pos = ((kk * 4 + quad) ^ (col & 7)) * 8;
      short8 af[2], bf[6];
#pragma unroll
      for (int mt = 0; mt < 2; mt++)
        af[mt] = *(const short8*)(Xc + (wave * 32 + mt * 16 + col) * 64 + pos);
#pragma unroll
      for (int nt = 0; nt < 6; nt++)
        bf[nt] = *(const short8*)(Ws + (nt * 16 + col) * 64 + pos);
#pragma unroll
      for (int mt = 0; mt < 2; mt++)
#pragma unroll
        for (int nt = 0; nt < 6; nt++)
          acc[mt][nt] = __builtin_amdgcn_mfma_f32_16x16x32_bf16(af[mt], bf[nt], acc[mt][nt], 0, 0, 0);
    }
  };

  // 16 tiles of BK=64; tile t's X in Xs[t&1]; iter computes t, prefetches t+1
#pragma unroll 1
  for (int tp = 0; tp < 8; tp++) {
    gemm_step((2 * tp + 1) * 64, Xs0, Xs1);                   // t = 2tp
    gemm_step((tp == 7) ? -1 : (2 * tp + 2) * 64, Xs1, Xs0);  // t = 2tp+1
  }

  // ---------------- phase 2: attention, 2 heads sequentially ----------------
  u16* const Qs = smem;               // [256][QKS]
  u16* const Ks = smem + 5120;        // [256][QKS]
  u16* const Vt = smem + 10240;       // [16][VTS]
  float* const l_s = (float*)(smem + 14464);
  float* const ot = (float*)smem;     // [16][257] f32, overlays Qs+Ks

#pragma unroll      // full unroll: h must be compile-time (static acc indices)
  for (int h = 0; h < 2; h++) {
    __syncthreads();  // h=0: GEMM reads done; h=1: prev ot/Vt reads done

    // C/D layout: row = m-base + quad*4 + r, col(head feature) = lane&15
#pragma unroll
    for (int mt = 0; mt < 2; mt++) {
      const int row = wave * 32 + mt * 16 + quad * 4;
#pragma unroll
      for (int r = 0; r < 4; r++) {
        Qs[(row + r) * QKS + col] = f2bf(acc[mt][3 * h + 0][r] * QSCALE);
        Ks[(row + r) * QKS + col] = f2bf(acc[mt][3 * h + 1][r]);
        Vt[col * VTS + row + r] = f2bf(acc[mt][3 * h + 2][r]);
      }
    }
    __syncthreads();

    const int q0 = wave * 32;
    short4v bq[2];
    float mqv[2];
#pragma unroll
    for (int qt = 0; qt < 2; qt++) {
      bq[qt] = *(const short4v*)(Qs + (q0 + qt * 16 + col) * QKS + quad * 4);
      mqv[qt] = m_s[q0 + qt * 16 + col];
    }

    floatx4 oacc[2] = {};
    floatx4 lacc[2] = {};
    if (allones)
      attn_loop2<false>(Ks, Vt, bq, mqv, m_s, oacc, lacc, col, quad);
    else
      attn_loop2<true>(Ks, Vt, bq, mqv, m_s, oacc, lacc, col, quad);

    __syncthreads();  // all waves out of attn before ot overlays Qs/Ks
#pragma unroll
    for (int qt = 0; qt < 2; qt++) {
      if (quad == 0) l_s[q0 + qt * 16 + col] = lacc[qt][0];
#pragma unroll
      for (int r = 0; r < 4; r++)
        ot[(quad * 4 + r) * 257 + q0 + qt * 16 + col] = oacc[qt][r];
    }
    __syncthreads();

    // epilogue: thread t -> q-row t>>1, features hb..hb+8; 32B coalesced
    const int row = t >> 1;
    const int hb = (t & 1) * 8;
    float l = l_s[row];
    float* op = out + ((size_t)b * 256 + row) * 1024 + (c0 + h) * 16 + hb;
    float o[8];
    if (allones || l > 0.f) {
      float inv = 1.0f / l;
#pragma unroll
      for (int j = 0; j < 8; j++) o[j] = ot[(hb + j) * 257 + row] * inv;
    } else {
      // fully-masked row: reference softmax of uniform -1e9 -> mean of V
#pragma unroll
      for (int j = 0; j < 8; j++) o[j] = 0.f;
      for (int k = 0; k < 256; k++)
#pragma unroll
        for (int j = 0; j < 8; j++) o[j] += bf2f(Vt[(hb + j) * VTS + k]);
#pragma unroll
      for (int j = 0; j < 8; j++) o[j] *= (1.0f / 256.0f);
    }
#pragma unroll
    for (int g = 0; g < 2; g++) {
      float4 r;
      r.x = o[g * 4 + 0]; r.y = o[g * 4 + 1]; r.z = o[g * 4 + 2]; r.w = o[g * 4 + 3];
      *(float4*)(op + g * 4) = r;
    }
  }
}

// ---------------------------------------------------------------------------
// Launch
// ---------------------------------------------------------------------------
extern "C" void kernel_launch(void* const* d_in, const int* in_sizes, int n_in,
                              void* d_out, int out_size, void* d_ws, size_t ws_size,
                              hipStream_t stream) {
  const float* x    = (const float*)d_in[0];  // [32,256,1024]
  const float* mask = (const float*)d_in[1];  // [32,256]
  const float* Wq   = (const float*)d_in[2];  // [1024,1024]
  const float* Wk   = (const float*)d_in[3];
  const float* Wv   = (const float*)d_in[4];
  float* out = (float*)d_out;

  u16* XB = (u16*)d_ws;                       // [8192][1024] bf16
  u16* WB = XB + (size_t)8192 * 1024;         // [3072][1024] (Wq,Wk,Wv stacked)

  cast_all<<<11264, 256, 0, stream>>>(x, Wq, Wk, Wv, XB, WB);
  fused_qkv_attn<<<1024, 512, 0, stream>>>(XB, WB, mask, out);
}